// Round 7
// baseline (319.264 us; speedup 1.0000x reference)
//
#include <hip/hip_runtime.h>
#include <hip/hip_bf16.h>
#include <math.h>

#define N_NODES 50000
#define N_EDGES 800000
// F_IN = HIDDEN = 128, N_CLASSES = 40

#define SCAN_CHUNK 512
#define SCAN_NB ((N_NODES + SCAN_CHUNK - 1) / SCAN_CHUNK)  // 98

// ---------------- degree histogram ----------------
// Indices clamped defensively: if the edge buffer dtype ever mismatches the
// harness contract (int32), we fail validation cleanly instead of faulting.
__global__ __launch_bounds__(256) void count_kernel(const int* __restrict__ ei,
                                                    int* __restrict__ cnt) {
  int e = blockIdx.x * 256 + threadIdx.x;
  if (e < N_EDGES) {
    int d = ei[N_EDGES + e];
    d = min(max(d, 0), N_NODES - 1);
    atomicAdd(&cnt[d], 1);
  }
}

// ---------------- 3-pass exclusive scan over cnt -> rowptr ----------------
__global__ __launch_bounds__(256) void scan_reduce(const int* __restrict__ cnt,
                                                   int* __restrict__ bsum) {
  __shared__ int s[256];
  int t = threadIdx.x;
  int i0 = blockIdx.x * SCAN_CHUNK + t * 2;
  int v = 0;
  if (i0 < N_NODES) v += cnt[i0];
  if (i0 + 1 < N_NODES) v += cnt[i0 + 1];
  s[t] = v;
  __syncthreads();
  for (int off = 128; off > 0; off >>= 1) {
    if (t < off) s[t] += s[t + off];
    __syncthreads();
  }
  if (t == 0) bsum[blockIdx.x] = s[0];
}

__global__ void scan_block(int* bsum) {
  __shared__ int s[128];
  int t = threadIdx.x;
  int v = (t < SCAN_NB) ? bsum[t] : 0;
  s[t] = v;
  __syncthreads();
  for (int off = 1; off < 128; off <<= 1) {
    int a = (t >= off) ? s[t - off] : 0;
    __syncthreads();
    s[t] += a;
    __syncthreads();
  }
  if (t < SCAN_NB) bsum[t] = s[t] - v;  // exclusive
}

__global__ __launch_bounds__(256) void scan_final(const int* __restrict__ cnt,
                                                  const int* __restrict__ bsum,
                                                  int* __restrict__ rowptr,
                                                  int* __restrict__ cursor,
                                                  float* __restrict__ dinv) {
  __shared__ int s[256];
  int t = threadIdx.x;
  int b = blockIdx.x;
  int i0 = b * SCAN_CHUNK + t * 2;
  int c0 = (i0 < N_NODES) ? cnt[i0] : 0;
  int c1 = (i0 + 1 < N_NODES) ? cnt[i0 + 1] : 0;
  int v = c0 + c1;
  s[t] = v;
  __syncthreads();
  for (int off = 1; off < 256; off <<= 1) {
    int a = (t >= off) ? s[t - off] : 0;
    __syncthreads();
    s[t] += a;
    __syncthreads();
  }
  int excl = s[t] - v + bsum[b];
  if (i0 < N_NODES) {
    rowptr[i0] = excl;
    cursor[i0] = excl;
    dinv[i0] = rsqrtf((float)(c0 + 1));  // deg includes self-loop, always > 0
  }
  if (i0 + 1 < N_NODES) {
    rowptr[i0 + 1] = excl + c0;
    cursor[i0 + 1] = excl + c0;
    dinv[i0 + 1] = rsqrtf((float)(c1 + 1));
  }
  if (b == 0 && t == 0) rowptr[N_NODES] = N_EDGES;
}

__global__ __launch_bounds__(256) void fill_kernel(const int* __restrict__ ei,
                                                   int* __restrict__ cursor,
                                                   int* __restrict__ col) {
  int e = blockIdx.x * 256 + threadIdx.x;
  if (e >= N_EDGES) return;
  int srcv = ei[e];
  int dstv = ei[N_EDGES + e];
  srcv = min(max(srcv, 0), N_NODES - 1);  // defensive clamp (see count_kernel)
  dstv = min(max(dstv, 0), N_NODES - 1);
  int p = atomicAdd(&cursor[dstv], 1);
  col[p] = srcv;
}

// ---------------- GEMM1: h1p = dinv .* (X @ W1)  [50000x128 @ 128x128] ----------------
// 128x128 tile/block, 4 waves as 2x2 of 64x64 wave tiles, 8x8 per thread.
// LDS: xs (rows x k) and ws (cols x k, i.e. W^T), both XOR-swizzled at 16B granularity
// so the 8 distinct row/col chunks a wave reads per ds_read_b128 hit disjoint banks.
__global__ __launch_bounds__(256) void gemm1_kernel(const float* __restrict__ X,
                                                    const float* __restrict__ W,
                                                    const float* __restrict__ dinv,
                                                    float* __restrict__ h1p) {
  __shared__ float xs[128 * 128];
  __shared__ float ws[128 * 128];
  int t = threadIdx.x;
  int row0 = blockIdx.x * 128;
#pragma unroll
  for (int it = 0; it < 16; ++it) {
    int idx = t + it * 256;
    int r = idx >> 5, kq = idx & 31;
    int gr = row0 + r;
    if (gr >= N_NODES) gr = N_NODES - 1;  // clamp; tail outputs are guarded
    float4 v = *(const float4*)(X + (size_t)gr * 128 + kq * 4);
    *(float4*)(xs + r * 128 + ((kq ^ (r & 7)) << 2)) = v;
  }
#pragma unroll
  for (int it = 0; it < 16; ++it) {
    int idx = t + it * 256;
    int k = idx >> 5, jq = idx & 31;
    float4 v = *(const float4*)(W + k * 128 + jq * 4);
    int kc = k >> 2, kr = k & 3;
    int j0 = jq * 4;
    ws[(j0 + 0) * 128 + (((kc ^ ((j0 + 0) & 7)) << 2) | kr)] = v.x;
    ws[(j0 + 1) * 128 + (((kc ^ ((j0 + 1) & 7)) << 2) | kr)] = v.y;
    ws[(j0 + 2) * 128 + (((kc ^ ((j0 + 2) & 7)) << 2) | kr)] = v.z;
    ws[(j0 + 3) * 128 + (((kc ^ ((j0 + 3) & 7)) << 2) | kr)] = v.w;
  }
  __syncthreads();
  int wv = t >> 6, lane = t & 63;
  int wr = (wv >> 1) << 6, wc = (wv & 1) << 6;
  int tr = lane >> 3, tc = lane & 7;
  float acc[8][8];
#pragma unroll
  for (int i = 0; i < 8; ++i)
#pragma unroll
    for (int m = 0; m < 8; ++m) acc[i][m] = 0.f;
  for (int kq = 0; kq < 32; ++kq) {
    float4 xv[8], wvv[8];
#pragma unroll
    for (int i = 0; i < 8; ++i)
      xv[i] = *(const float4*)(xs + (wr + tr + 8 * i) * 128 + ((kq ^ tr) << 2));
#pragma unroll
    for (int m = 0; m < 8; ++m)
      wvv[m] = *(const float4*)(ws + (wc + tc + 8 * m) * 128 + ((kq ^ tc) << 2));
#pragma unroll
    for (int i = 0; i < 8; ++i)
#pragma unroll
      for (int m = 0; m < 8; ++m) {
        acc[i][m] = fmaf(xv[i].x, wvv[m].x, acc[i][m]);
        acc[i][m] = fmaf(xv[i].y, wvv[m].y, acc[i][m]);
        acc[i][m] = fmaf(xv[i].z, wvv[m].z, acc[i][m]);
        acc[i][m] = fmaf(xv[i].w, wvv[m].w, acc[i][m]);
      }
  }
#pragma unroll
  for (int i = 0; i < 8; ++i) {
    int gr = row0 + wr + tr + 8 * i;
    if (gr < N_NODES) {
      float di = dinv[gr];
#pragma unroll
      for (int m = 0; m < 8; ++m)
        h1p[(size_t)gr * 128 + wc + tc + 8 * m] = di * acc[i][m];
    }
  }
}

// ---------------- layer-1 aggregation: x2 = relu(dinv.*(h1p + gather-sum) + b1) ------
__global__ __launch_bounds__(256) void agg1_kernel(const float* __restrict__ h1p,
                                                   const int* __restrict__ rowptr,
                                                   const int* __restrict__ col,
                                                   const float* __restrict__ dinv,
                                                   const float* __restrict__ b1,
                                                   float* __restrict__ x2) {
  int wid = (blockIdx.x * 256 + threadIdx.x) >> 6;  // one wave per node
  int lane = threadIdx.x & 63;
  if (wid >= N_NODES) return;
  int rs = rowptr[wid], re = rowptr[wid + 1];
  int f = lane * 2;
  const float2* hp2 = (const float2*)h1p;
  float2 acc = hp2[(size_t)wid * 64 + lane];  // self-loop term
  for (int base = rs; base < re; base += 64) {
    int idx = base + lane;
    int c = (idx < re) ? col[idx] : 0;
    int nb = min(64, re - base);
    int e = 0;
    for (; e + 4 <= nb; e += 4) {
      int s0 = __shfl(c, e), s1 = __shfl(c, e + 1);
      int s2 = __shfl(c, e + 2), s3 = __shfl(c, e + 3);
      float2 v0 = hp2[(size_t)s0 * 64 + lane];
      float2 v1 = hp2[(size_t)s1 * 64 + lane];
      float2 v2 = hp2[(size_t)s2 * 64 + lane];
      float2 v3 = hp2[(size_t)s3 * 64 + lane];
      acc.x += (v0.x + v1.x) + (v2.x + v3.x);
      acc.y += (v0.y + v1.y) + (v2.y + v3.y);
    }
    for (; e < nb; ++e) {
      int s0 = __shfl(c, e);
      float2 v0 = hp2[(size_t)s0 * 64 + lane];
      acc.x += v0.x;
      acc.y += v0.y;
    }
  }
  float di = dinv[wid];
  float2 o;
  o.x = fmaxf(fmaf(di, acc.x, b1[f]), 0.f);
  o.y = fmaxf(fmaf(di, acc.y, b1[f + 1]), 0.f);
  *(float2*)(x2 + (size_t)wid * 128 + f) = o;
}

// ---------------- GEMM2: h2p = dinv .* (x2 @ W2)  [50000x128 @ 128x40] ----------------
// 64-row tile/block, wave handles 16 rows; thread: 2 rows x 5 cols.
__global__ __launch_bounds__(256) void gemm2_kernel(const float* __restrict__ X2,
                                                    const float* __restrict__ W2,
                                                    const float* __restrict__ dinv,
                                                    float* __restrict__ h2p) {
  __shared__ float xs[64 * 128];
  __shared__ float ws[40 * 128];
  int t = threadIdx.x;
  int row0 = blockIdx.x * 64;
#pragma unroll
  for (int it = 0; it < 8; ++it) {
    int idx = t + it * 256;
    int r = idx >> 5, kq = idx & 31;
    int gr = row0 + r;
    if (gr >= N_NODES) gr = N_NODES - 1;
    float4 v = *(const float4*)(X2 + (size_t)gr * 128 + kq * 4);
    *(float4*)(xs + r * 128 + ((kq ^ (r & 7)) << 2)) = v;
  }
  for (int idx = t; idx < 1280; idx += 256) {  // W2: [128][40] -> ws[j][swz(k)]
    int k = idx / 10, jq = idx % 10;
    float4 v = *(const float4*)(W2 + k * 40 + jq * 4);
    int kc = k >> 2, kr = k & 3;
    int j0 = jq * 4;
    ws[(j0 + 0) * 128 + (((kc ^ ((j0 + 0) & 7)) << 2) | kr)] = v.x;
    ws[(j0 + 1) * 128 + (((kc ^ ((j0 + 1) & 7)) << 2) | kr)] = v.y;
    ws[(j0 + 2) * 128 + (((kc ^ ((j0 + 2) & 7)) << 2) | kr)] = v.z;
    ws[(j0 + 3) * 128 + (((kc ^ ((j0 + 3) & 7)) << 2) | kr)] = v.w;
  }
  __syncthreads();
  int wv = t >> 6, lane = t & 63;
  int tr = lane >> 3, tc = lane & 7;
  int rbase = wv * 16;
  float acc[2][5];
#pragma unroll
  for (int i = 0; i < 2; ++i)
#pragma unroll
    for (int m = 0; m < 5; ++m) acc[i][m] = 0.f;
  for (int kq = 0; kq < 32; ++kq) {
    float4 xv[2], wvv[5];
#pragma unroll
    for (int i = 0; i < 2; ++i)
      xv[i] = *(const float4*)(xs + (rbase + tr + 8 * i) * 128 + ((kq ^ tr) << 2));
#pragma unroll
    for (int m = 0; m < 5; ++m)
      wvv[m] = *(const float4*)(ws + (tc + 8 * m) * 128 + ((kq ^ tc) << 2));
#pragma unroll
    for (int i = 0; i < 2; ++i)
#pragma unroll
      for (int m = 0; m < 5; ++m) {
        acc[i][m] = fmaf(xv[i].x, wvv[m].x, acc[i][m]);
        acc[i][m] = fmaf(xv[i].y, wvv[m].y, acc[i][m]);
        acc[i][m] = fmaf(xv[i].z, wvv[m].z, acc[i][m]);
        acc[i][m] = fmaf(xv[i].w, wvv[m].w, acc[i][m]);
      }
  }
#pragma unroll
  for (int i = 0; i < 2; ++i) {
    int gr = row0 + rbase + tr + 8 * i;
    if (gr < N_NODES) {
      float di = dinv[gr];
#pragma unroll
      for (int m = 0; m < 5; ++m)
        h2p[(size_t)gr * 40 + tc + 8 * m] = di * acc[i][m];
    }
  }
}

// ------- layer-2 aggregation fused with bias + log_softmax, writes d_out -------
__global__ __launch_bounds__(256) void agg2_softmax_kernel(const float* __restrict__ h2p,
                                                           const int* __restrict__ rowptr,
                                                           const int* __restrict__ col,
                                                           const float* __restrict__ dinv,
                                                           const float* __restrict__ b2,
                                                           float* __restrict__ out) {
  int wid = (blockIdx.x * 256 + threadIdx.x) >> 6;  // one wave per node
  int lane = threadIdx.x & 63;
  if (wid >= N_NODES) return;
  int rs = rowptr[wid], re = rowptr[wid + 1];
  bool act = lane < 40;
  float acc = act ? h2p[(size_t)wid * 40 + lane] : 0.f;
  for (int base = rs; base < re; base += 64) {
    int idx = base + lane;
    int c = (idx < re) ? col[idx] : 0;
    int nb = min(64, re - base);
    int e = 0;
    for (; e + 4 <= nb; e += 4) {
      int s0 = __shfl(c, e), s1 = __shfl(c, e + 1);
      int s2 = __shfl(c, e + 2), s3 = __shfl(c, e + 3);
      if (act) {
        float v0 = h2p[(size_t)s0 * 40 + lane];
        float v1 = h2p[(size_t)s1 * 40 + lane];
        float v2 = h2p[(size_t)s2 * 40 + lane];
        float v3 = h2p[(size_t)s3 * 40 + lane];
        acc += (v0 + v1) + (v2 + v3);
      }
    }
    for (; e < nb; ++e) {
      int s0 = __shfl(c, e);
      if (act) acc += h2p[(size_t)s0 * 40 + lane];
    }
  }
  float v = act ? fmaf(dinv[wid], acc, b2[lane]) : -1e30f;
  float m = v;
#pragma unroll
  for (int off = 32; off > 0; off >>= 1) m = fmaxf(m, __shfl_xor(m, off));
  float ex = act ? expf(v - m) : 0.f;
  float ssum = ex;
#pragma unroll
  for (int off = 32; off > 0; off >>= 1) ssum += __shfl_xor(ssum, off);
  float ls = logf(ssum);
  if (act) out[(size_t)wid * 40 + lane] = v - m - ls;
}

extern "C" void kernel_launch(void* const* d_in, const int* in_sizes, int n_in,
                              void* d_out, int out_size, void* d_ws, size_t ws_size,
                              hipStream_t stream) {
  const float* X = (const float*)d_in[0];
  const int* ei = (const int*)d_in[1];  // [2][E] int32 per harness contract
  const float* W1 = (const float*)d_in[2];
  const float* b1 = (const float*)d_in[3];
  const float* W2 = (const float*)d_in[4];
  const float* b2 = (const float*)d_in[5];
  float* out = (float*)d_out;

  char* p = (char*)d_ws;
  auto carve = [&](size_t bytes) -> void* {
    void* q = (void*)p;
    p += (bytes + 255) & ~(size_t)255;
    return q;
  };
  float* h1p = (float*)carve((size_t)N_NODES * 128 * 4);   // 25.6 MB
  float* x2 = (float*)carve((size_t)N_NODES * 128 * 4);    // 25.6 MB
  float* h2p = (float*)carve((size_t)N_NODES * 40 * 4);    // 8 MB
  int* col = (int*)carve((size_t)N_EDGES * 4);             // 3.2 MB
  int* cnt = (int*)carve((size_t)N_NODES * 4);
  int* rowptr = (int*)carve((size_t)(N_NODES + 1) * 4);
  int* cursor = (int*)carve((size_t)N_NODES * 4);
  float* dinv = (float*)carve((size_t)N_NODES * 4);
  int* bsum = (int*)carve((size_t)SCAN_NB * 4);

  hipMemsetAsync(cnt, 0, (size_t)N_NODES * 4, stream);
  count_kernel<<<(N_EDGES + 255) / 256, 256, 0, stream>>>(ei, cnt);
  scan_reduce<<<SCAN_NB, 256, 0, stream>>>(cnt, bsum);
  scan_block<<<1, 128, 0, stream>>>(bsum);
  scan_final<<<SCAN_NB, 256, 0, stream>>>(cnt, bsum, rowptr, cursor, dinv);
  fill_kernel<<<(N_EDGES + 255) / 256, 256, 0, stream>>>(ei, cursor, col);
  gemm1_kernel<<<(N_NODES + 127) / 128, 256, 0, stream>>>(X, W1, dinv, h1p);
  agg1_kernel<<<(N_NODES + 3) / 4, 256, 0, stream>>>(h1p, rowptr, col, dinv, b1, x2);
  gemm2_kernel<<<(N_NODES + 63) / 64, 256, 0, stream>>>(x2, W2, dinv, h2p);
  agg2_softmax_kernel<<<(N_NODES + 3) / 4, 256, 0, stream>>>(h2p, rowptr, col, dinv, b2, out);
}

// Round 8
// 314.439 us; speedup vs baseline: 1.0153x; 1.0153x over previous
//
#include <hip/hip_runtime.h>
#include <hip/hip_bf16.h>
#include <math.h>

#define N_NODES 50000
#define N_EDGES 800000
// F_IN = HIDDEN = 128, N_CLASSES = 40

#define SCAN_CHUNK 512
#define SCAN_NB ((N_NODES + SCAN_CHUNK - 1) / SCAN_CHUNK)  // 98

// ---------------- degree histogram ----------------
__global__ __launch_bounds__(256) void count_kernel(const int* __restrict__ ei,
                                                    int* __restrict__ cnt) {
  int e = blockIdx.x * 256 + threadIdx.x;
  if (e < N_EDGES) {
    int d = ei[N_EDGES + e];
    d = min(max(d, 0), N_NODES - 1);  // defensive clamp
    atomicAdd(&cnt[d], 1);
  }
}

// ---------------- 3-pass exclusive scan over cnt -> rowptr ----------------
__global__ __launch_bounds__(256) void scan_reduce(const int* __restrict__ cnt,
                                                   int* __restrict__ bsum) {
  __shared__ int s[256];
  int t = threadIdx.x;
  int i0 = blockIdx.x * SCAN_CHUNK + t * 2;
  int v = 0;
  if (i0 < N_NODES) v += cnt[i0];
  if (i0 + 1 < N_NODES) v += cnt[i0 + 1];
  s[t] = v;
  __syncthreads();
  for (int off = 128; off > 0; off >>= 1) {
    if (t < off) s[t] += s[t + off];
    __syncthreads();
  }
  if (t == 0) bsum[blockIdx.x] = s[0];
}

__global__ void scan_block(int* bsum) {
  __shared__ int s[128];
  int t = threadIdx.x;
  int v = (t < SCAN_NB) ? bsum[t] : 0;
  s[t] = v;
  __syncthreads();
  for (int off = 1; off < 128; off <<= 1) {
    int a = (t >= off) ? s[t - off] : 0;
    __syncthreads();
    s[t] += a;
    __syncthreads();
  }
  if (t < SCAN_NB) bsum[t] = s[t] - v;  // exclusive
}

__global__ __launch_bounds__(256) void scan_final(const int* __restrict__ cnt,
                                                  const int* __restrict__ bsum,
                                                  int* __restrict__ rowptr,
                                                  int* __restrict__ cursor,
                                                  float* __restrict__ dinv) {
  __shared__ int s[256];
  int t = threadIdx.x;
  int b = blockIdx.x;
  int i0 = b * SCAN_CHUNK + t * 2;
  int c0 = (i0 < N_NODES) ? cnt[i0] : 0;
  int c1 = (i0 + 1 < N_NODES) ? cnt[i0 + 1] : 0;
  int v = c0 + c1;
  s[t] = v;
  __syncthreads();
  for (int off = 1; off < 256; off <<= 1) {
    int a = (t >= off) ? s[t - off] : 0;
    __syncthreads();
    s[t] += a;
    __syncthreads();
  }
  int excl = s[t] - v + bsum[b];
  if (i0 < N_NODES) {
    rowptr[i0] = excl;
    cursor[i0] = excl;
    dinv[i0] = rsqrtf((float)(c0 + 1));  // deg includes self-loop, always > 0
  }
  if (i0 + 1 < N_NODES) {
    rowptr[i0 + 1] = excl + c0;
    cursor[i0 + 1] = excl + c0;
    dinv[i0 + 1] = rsqrtf((float)(c1 + 1));
  }
  if (b == 0 && t == 0) rowptr[N_NODES] = N_EDGES;
}

__global__ __launch_bounds__(256) void fill_kernel(const int* __restrict__ ei,
                                                   int* __restrict__ cursor,
                                                   int* __restrict__ col) {
  int e = blockIdx.x * 256 + threadIdx.x;
  if (e >= N_EDGES) return;
  int srcv = ei[e];
  int dstv = ei[N_EDGES + e];
  srcv = min(max(srcv, 0), N_NODES - 1);
  dstv = min(max(dstv, 0), N_NODES - 1);
  int p = atomicAdd(&cursor[dstv], 1);
  col[p] = srcv;
}

// ---------------- GEMM1: h1p = dinv .* (X @ W1)  [50000x128 @ 128x128] ----------------
// 128x128 tile/block, BK=64 two-stage K loop -> 64 KiB LDS -> 2 blocks/CU
// (was 128 KiB -> 1 wave/SIMD, no latency hiding). Same XOR swizzle, stride 64.
__global__ __launch_bounds__(256) void gemm1_kernel(const float* __restrict__ X,
                                                    const float* __restrict__ W,
                                                    const float* __restrict__ dinv,
                                                    float* __restrict__ h1p) {
  __shared__ float xs[128 * 64];
  __shared__ float ws[128 * 64];
  int t = threadIdx.x;
  int row0 = blockIdx.x * 128;
  int wv = t >> 6, lane = t & 63;
  int wr = (wv >> 1) << 6, wc = (wv & 1) << 6;
  int tr = lane >> 3, tc = lane & 7;
  float acc[8][8];
#pragma unroll
  for (int i = 0; i < 8; ++i)
#pragma unroll
    for (int m = 0; m < 8; ++m) acc[i][m] = 0.f;

  for (int h = 0; h < 2; ++h) {  // K halves: k in [h*64, h*64+64)
    if (h) __syncthreads();      // protect LDS reuse
#pragma unroll
    for (int it = 0; it < 8; ++it) {  // X tile: 128 rows x 16 quads
      int idx = t + it * 256;
      int r = idx >> 4, kq = idx & 15;
      int gr = row0 + r;
      if (gr >= N_NODES) gr = N_NODES - 1;  // clamp; tail outputs guarded
      float4 v = *(const float4*)(X + (size_t)gr * 128 + h * 64 + kq * 4);
      *(float4*)(xs + r * 64 + ((kq ^ (r & 7)) << 2)) = v;
    }
#pragma unroll
    for (int it = 0; it < 8; ++it) {  // W tile: 64 k x 32 j-quads -> ws[j][swz(k)]
      int idx = t + it * 256;
      int k = idx >> 5, jq = idx & 31;
      float4 v = *(const float4*)(W + (size_t)(h * 64 + k) * 128 + jq * 4);
      int kc = k >> 2, kr = k & 3;
      int j0 = jq * 4;
      ws[(j0 + 0) * 64 + (((kc ^ ((j0 + 0) & 7)) << 2) | kr)] = v.x;
      ws[(j0 + 1) * 64 + (((kc ^ ((j0 + 1) & 7)) << 2) | kr)] = v.y;
      ws[(j0 + 2) * 64 + (((kc ^ ((j0 + 2) & 7)) << 2) | kr)] = v.z;
      ws[(j0 + 3) * 64 + (((kc ^ ((j0 + 3) & 7)) << 2) | kr)] = v.w;
    }
    __syncthreads();
    for (int kq = 0; kq < 16; ++kq) {
      float4 xv[8], wvv[8];
#pragma unroll
      for (int i = 0; i < 8; ++i)
        xv[i] = *(const float4*)(xs + (wr + tr + 8 * i) * 64 + ((kq ^ tr) << 2));
#pragma unroll
      for (int m = 0; m < 8; ++m)
        wvv[m] = *(const float4*)(ws + (wc + tc + 8 * m) * 64 + ((kq ^ tc) << 2));
#pragma unroll
      for (int i = 0; i < 8; ++i)
#pragma unroll
        for (int m = 0; m < 8; ++m) {
          acc[i][m] = fmaf(xv[i].x, wvv[m].x, acc[i][m]);
          acc[i][m] = fmaf(xv[i].y, wvv[m].y, acc[i][m]);
          acc[i][m] = fmaf(xv[i].z, wvv[m].z, acc[i][m]);
          acc[i][m] = fmaf(xv[i].w, wvv[m].w, acc[i][m]);
        }
    }
  }
#pragma unroll
  for (int i = 0; i < 8; ++i) {
    int gr = row0 + wr + tr + 8 * i;
    if (gr < N_NODES) {
      float di = dinv[gr];
#pragma unroll
      for (int m = 0; m < 8; ++m)
        h1p[(size_t)gr * 128 + wc + tc + 8 * m] = di * acc[i][m];
    }
  }
}

// ---------------- layer-1 aggregation: x2 = relu(dinv.*(h1p + gather-sum) + b1) ------
// Half-wave per row: lanes 0-31 gather row e, lanes 32-63 row e+1, float4/lane.
// 4 independent accumulators -> ~4x more loads in flight (old version: VGPR=20,
// dep-chained 8B loads, 47% of HBM peak).
__global__ __launch_bounds__(256) void agg1_kernel(const float* __restrict__ h1p,
                                                   const int* __restrict__ rowptr,
                                                   const int* __restrict__ col,
                                                   const float* __restrict__ dinv,
                                                   const float* __restrict__ b1,
                                                   float* __restrict__ x2) {
  int wid = (blockIdx.x * 256 + threadIdx.x) >> 6;  // one wave per node
  int lane = threadIdx.x & 63;
  if (wid >= N_NODES) return;
  int rs = rowptr[wid], re = rowptr[wid + 1];
  int half = lane >> 5;  // 0: even edge of pair, 1: odd
  int fl = lane & 31;    // feature-quad index (4 floats each)
  const float4* hp4 = (const float4*)h1p;
  float4 z = {0.f, 0.f, 0.f, 0.f};
  // self-loop term folded into a0 on the low half only
  float4 a0 = (half == 0) ? hp4[(size_t)wid * 32 + fl] : z;
  float4 a1 = z, a2 = z, a3 = z;
  for (int base = rs; base < re; base += 64) {
    int idx = base + lane;
    int c = (idx < re) ? col[idx] : 0;
    int nb = min(64, re - base);
    int e = 0;
    for (; e + 8 <= nb; e += 8) {
      int s0 = __shfl(c, e + half);
      int s1 = __shfl(c, e + 2 + half);
      int s2 = __shfl(c, e + 4 + half);
      int s3 = __shfl(c, e + 6 + half);
      float4 v0 = hp4[(size_t)s0 * 32 + fl];
      float4 v1 = hp4[(size_t)s1 * 32 + fl];
      float4 v2 = hp4[(size_t)s2 * 32 + fl];
      float4 v3 = hp4[(size_t)s3 * 32 + fl];
      a0.x += v0.x; a0.y += v0.y; a0.z += v0.z; a0.w += v0.w;
      a1.x += v1.x; a1.y += v1.y; a1.z += v1.z; a1.w += v1.w;
      a2.x += v2.x; a2.y += v2.y; a2.z += v2.z; a2.w += v2.w;
      a3.x += v3.x; a3.y += v3.y; a3.z += v3.z; a3.w += v3.w;
    }
    for (; e + 2 <= nb; e += 2) {
      int s0 = __shfl(c, e + half);
      float4 v0 = hp4[(size_t)s0 * 32 + fl];
      a0.x += v0.x; a0.y += v0.y; a0.z += v0.z; a0.w += v0.w;
    }
    if (e < nb) {  // odd remainder: low half only (avoid double count)
      int s0 = __shfl(c, e);
      if (half == 0) {
        float4 v0 = hp4[(size_t)s0 * 32 + fl];
        a0.x += v0.x; a0.y += v0.y; a0.z += v0.z; a0.w += v0.w;
      }
    }
  }
  float4 a;
  a.x = (a0.x + a1.x) + (a2.x + a3.x);
  a.y = (a0.y + a1.y) + (a2.y + a3.y);
  a.z = (a0.z + a1.z) + (a2.z + a3.z);
  a.w = (a0.w + a1.w) + (a2.w + a3.w);
  // fold odd-half partial sums into lanes 0-31
  a.x += __shfl_xor(a.x, 32);
  a.y += __shfl_xor(a.y, 32);
  a.z += __shfl_xor(a.z, 32);
  a.w += __shfl_xor(a.w, 32);
  if (half == 0) {
    float di = dinv[wid];
    float4 bb = ((const float4*)b1)[fl];
    float4 o;
    o.x = fmaxf(fmaf(di, a.x, bb.x), 0.f);
    o.y = fmaxf(fmaf(di, a.y, bb.y), 0.f);
    o.z = fmaxf(fmaf(di, a.z, bb.z), 0.f);
    o.w = fmaxf(fmaf(di, a.w, bb.w), 0.f);
    *(float4*)(x2 + (size_t)wid * 128 + fl * 4) = o;
  }
}

// ---------------- GEMM2: h2p = dinv .* (x2 @ W2)  [50000x128 @ 128x40] ----------------
__global__ __launch_bounds__(256) void gemm2_kernel(const float* __restrict__ X2,
                                                    const float* __restrict__ W2,
                                                    const float* __restrict__ dinv,
                                                    float* __restrict__ h2p) {
  __shared__ float xs[64 * 128];
  __shared__ float ws[40 * 128];
  int t = threadIdx.x;
  int row0 = blockIdx.x * 64;
#pragma unroll
  for (int it = 0; it < 8; ++it) {
    int idx = t + it * 256;
    int r = idx >> 5, kq = idx & 31;
    int gr = row0 + r;
    if (gr >= N_NODES) gr = N_NODES - 1;
    float4 v = *(const float4*)(X2 + (size_t)gr * 128 + kq * 4);
    *(float4*)(xs + r * 128 + ((kq ^ (r & 7)) << 2)) = v;
  }
  for (int idx = t; idx < 1280; idx += 256) {  // W2: [128][40] -> ws[j][swz(k)]
    int k = idx / 10, jq = idx % 10;
    float4 v = *(const float4*)(W2 + k * 40 + jq * 4);
    int kc = k >> 2, kr = k & 3;
    int j0 = jq * 4;
    ws[(j0 + 0) * 128 + (((kc ^ ((j0 + 0) & 7)) << 2) | kr)] = v.x;
    ws[(j0 + 1) * 128 + (((kc ^ ((j0 + 1) & 7)) << 2) | kr)] = v.y;
    ws[(j0 + 2) * 128 + (((kc ^ ((j0 + 2) & 7)) << 2) | kr)] = v.z;
    ws[(j0 + 3) * 128 + (((kc ^ ((j0 + 3) & 7)) << 2) | kr)] = v.w;
  }
  __syncthreads();
  int wv = t >> 6, lane = t & 63;
  int tr = lane >> 3, tc = lane & 7;
  int rbase = wv * 16;
  float acc[2][5];
#pragma unroll
  for (int i = 0; i < 2; ++i)
#pragma unroll
    for (int m = 0; m < 5; ++m) acc[i][m] = 0.f;
  for (int kq = 0; kq < 32; ++kq) {
    float4 xv[2], wvv[5];
#pragma unroll
    for (int i = 0; i < 2; ++i)
      xv[i] = *(const float4*)(xs + (rbase + tr + 8 * i) * 128 + ((kq ^ tr) << 2));
#pragma unroll
    for (int m = 0; m < 5; ++m)
      wvv[m] = *(const float4*)(ws + (tc + 8 * m) * 128 + ((kq ^ tc) << 2));
#pragma unroll
    for (int i = 0; i < 2; ++i)
#pragma unroll
      for (int m = 0; m < 5; ++m) {
        acc[i][m] = fmaf(xv[i].x, wvv[m].x, acc[i][m]);
        acc[i][m] = fmaf(xv[i].y, wvv[m].y, acc[i][m]);
        acc[i][m] = fmaf(xv[i].z, wvv[m].z, acc[i][m]);
        acc[i][m] = fmaf(xv[i].w, wvv[m].w, acc[i][m]);
      }
  }
#pragma unroll
  for (int i = 0; i < 2; ++i) {
    int gr = row0 + rbase + tr + 8 * i;
    if (gr < N_NODES) {
      float di = dinv[gr];
#pragma unroll
      for (int m = 0; m < 5; ++m)
        h2p[(size_t)gr * 40 + tc + 8 * m] = di * acc[i][m];
    }
  }
}

// ------- layer-2 aggregation fused with bias + log_softmax, writes d_out -------
__global__ __launch_bounds__(256) void agg2_softmax_kernel(const float* __restrict__ h2p,
                                                           const int* __restrict__ rowptr,
                                                           const int* __restrict__ col,
                                                           const float* __restrict__ dinv,
                                                           const float* __restrict__ b2,
                                                           float* __restrict__ out) {
  int wid = (blockIdx.x * 256 + threadIdx.x) >> 6;  // one wave per node
  int lane = threadIdx.x & 63;
  if (wid >= N_NODES) return;
  int rs = rowptr[wid], re = rowptr[wid + 1];
  bool act = lane < 40;
  // 4 independent accumulator chains
  float ac0 = act ? h2p[(size_t)wid * 40 + lane] : 0.f;
  float ac1 = 0.f, ac2 = 0.f, ac3 = 0.f;
  for (int base = rs; base < re; base += 64) {
    int idx = base + lane;
    int c = (idx < re) ? col[idx] : 0;
    int nb = min(64, re - base);
    int e = 0;
    for (; e + 4 <= nb; e += 4) {
      int s0 = __shfl(c, e), s1 = __shfl(c, e + 1);
      int s2 = __shfl(c, e + 2), s3 = __shfl(c, e + 3);
      if (act) {
        ac0 += h2p[(size_t)s0 * 40 + lane];
        ac1 += h2p[(size_t)s1 * 40 + lane];
        ac2 += h2p[(size_t)s2 * 40 + lane];
        ac3 += h2p[(size_t)s3 * 40 + lane];
      }
    }
    for (; e < nb; ++e) {
      int s0 = __shfl(c, e);
      if (act) ac0 += h2p[(size_t)s0 * 40 + lane];
    }
  }
  float acc = (ac0 + ac1) + (ac2 + ac3);
  float v = act ? fmaf(dinv[wid], acc, b2[lane]) : -1e30f;
  float m = v;
#pragma unroll
  for (int off = 32; off > 0; off >>= 1) m = fmaxf(m, __shfl_xor(m, off));
  float ex = act ? expf(v - m) : 0.f;
  float ssum = ex;
#pragma unroll
  for (int off = 32; off > 0; off >>= 1) ssum += __shfl_xor(ssum, off);
  float ls = logf(ssum);
  if (act) out[(size_t)wid * 40 + lane] = v - m - ls;
}

extern "C" void kernel_launch(void* const* d_in, const int* in_sizes, int n_in,
                              void* d_out, int out_size, void* d_ws, size_t ws_size,
                              hipStream_t stream) {
  const float* X = (const float*)d_in[0];
  const int* ei = (const int*)d_in[1];  // [2][E] int32 per harness contract
  const float* W1 = (const float*)d_in[2];
  const float* b1 = (const float*)d_in[3];
  const float* W2 = (const float*)d_in[4];
  const float* b2 = (const float*)d_in[5];
  float* out = (float*)d_out;

  char* p = (char*)d_ws;
  auto carve = [&](size_t bytes) -> void* {
    void* q = (void*)p;
    p += (bytes + 255) & ~(size_t)255;
    return q;
  };
  float* h1p = (float*)carve((size_t)N_NODES * 128 * 4);   // 25.6 MB
  float* x2 = (float*)carve((size_t)N_NODES * 128 * 4);    // 25.6 MB
  float* h2p = (float*)carve((size_t)N_NODES * 40 * 4);    // 8 MB
  int* col = (int*)carve((size_t)N_EDGES * 4);             // 3.2 MB
  int* cnt = (int*)carve((size_t)N_NODES * 4);
  int* rowptr = (int*)carve((size_t)(N_NODES + 1) * 4);
  int* cursor = (int*)carve((size_t)N_NODES * 4);
  float* dinv = (float*)carve((size_t)N_NODES * 4);
  int* bsum = (int*)carve((size_t)SCAN_NB * 4);

  hipMemsetAsync(cnt, 0, (size_t)N_NODES * 4, stream);
  count_kernel<<<(N_EDGES + 255) / 256, 256, 0, stream>>>(ei, cnt);
  scan_reduce<<<SCAN_NB, 256, 0, stream>>>(cnt, bsum);
  scan_block<<<1, 128, 0, stream>>>(bsum);
  scan_final<<<SCAN_NB, 256, 0, stream>>>(cnt, bsum, rowptr, cursor, dinv);
  fill_kernel<<<(N_EDGES + 255) / 256, 256, 0, stream>>>(ei, cursor, col);
  gemm1_kernel<<<(N_NODES + 127) / 128, 256, 0, stream>>>(X, W1, dinv, h1p);
  agg1_kernel<<<(N_NODES + 3) / 4, 256, 0, stream>>>(h1p, rowptr, col, dinv, b1, x2);
  gemm2_kernel<<<(N_NODES + 63) / 64, 256, 0, stream>>>(x2, W2, dinv, h2p);
  agg2_softmax_kernel<<<(N_NODES + 3) / 4, 256, 0, stream>>>(h2p, rowptr, col, dinv, b2, out);
}